// Round 1
// baseline (76.700 us; speedup 1.0000x reference)
//
#include <hip/hip_runtime.h>
#include <math.h>

#ifndef M_PI
#define M_PI 3.14159265358979323846
#endif

#define NPTS 8192
#define KCOMP 64
#define JT 256      // j-tile per block
#define IBLK 256    // i's per block (= block size)

#if __has_builtin(__builtin_amdgcn_exp2f)
#define EXP2(x) __builtin_amdgcn_exp2f(x)
#else
#define EXP2(x) exp2f(x)
#endif

// workspace layout (floats): [0,64) amp | [64,128) q | [128,128+8192) data_sum

// --- Kernel A: softmax(weight_logits) -> amplitude & exponent coefs (1 wave) ---
__global__ __launch_bounds__(64) void prep_kernel(
    const float* __restrict__ logits,
    const float* __restrict__ log_vars,
    float* __restrict__ amp,
    float* __restrict__ q) {
  int k = threadIdx.x;  // 0..63
  float l = logits[k];
  float m = l;
#pragma unroll
  for (int off = 32; off > 0; off >>= 1)
    m = fmaxf(m, __shfl_xor(m, off));
  float e = expf(l - m);
  float ssum = e;
#pragma unroll
  for (int off = 32; off > 0; off >>= 1)
    ssum += __shfl_xor(ssum, off);
  float w = e / ssum;
  float var = expf(log_vars[k]);
  // component pdf = amp * 2^(-q * d^2)
  amp[k] = w * rsqrtf(2.0f * (float)M_PI * var);
  q[k]   = 0.72134752044448170368f / var;  // 0.5 * log2(e) / var
}

// --- Kernel B: pairwise KDE partial sums (the 67M-exp workhorse) ---
__global__ __launch_bounds__(IBLK) void kde_kernel(
    const float* __restrict__ x,
    float* __restrict__ data_sum) {
  __shared__ float xs[JT];
  // kern = exp(-0.5 d^2 / bw^2) = 2^(-(s*d)^2), s = sqrt(8192 * log2(e))
  const float s = sqrtf(8192.0f * 1.44269504088896340736f);
  const int t  = threadIdx.x;
  const int i  = blockIdx.x * IBLK + t;
  const int j0 = blockIdx.y * JT;
  xs[t] = x[j0 + t] * s;          // pre-scaled j-tile
  float u = x[i] * s;             // pre-scaled own point
  __syncthreads();

  float acc0 = 0.f, acc1 = 0.f, acc2 = 0.f, acc3 = 0.f;
  const float4* xs4 = reinterpret_cast<const float4*>(xs);
#pragma unroll 4
  for (int jj = 0; jj < JT / 4; ++jj) {
    float4 v = xs4[jj];           // ds_read_b128 broadcast
    float d0 = u - v.x;
    float d1 = u - v.y;
    float d2 = u - v.z;
    float d3 = u - v.w;
    acc0 += EXP2(-(d0 * d0));     // v_mul (neg mod) + v_exp + v_add
    acc1 += EXP2(-(d1 * d1));
    acc2 += EXP2(-(d2 * d2));
    acc3 += EXP2(-(d3 * d3));
  }
  atomicAdd(&data_sum[i], (acc0 + acc1) + (acc2 + acc3));
}

// --- Kernel C: mixture pdf + squared-diff reduction ---
__global__ __launch_bounds__(256) void final_kernel(
    const float* __restrict__ x,
    const float* __restrict__ means,
    const float* __restrict__ amp,
    const float* __restrict__ q,
    const float* __restrict__ data_sum,
    float* __restrict__ out) {
  __shared__ float sm[KCOMP], sa[KCOMP], sq[KCOMP];
  const int t = threadIdx.x;
  if (t < KCOMP) { sm[t] = means[t]; sa[t] = amp[t]; sq[t] = q[t]; }
  __syncthreads();

  const int i = blockIdx.x * 256 + t;
  const float xi = x[i];
  float mix = 0.f;
#pragma unroll 8
  for (int k = 0; k < KCOMP; ++k) {
    float d = xi - sm[k];
    mix += sa[k] * EXP2(-(sq[k] * d) * d);
  }
  // data_pdf = sum / (sqrt(2*pi*bw^2) * N) ; sqrt(2pi)*bw*N = sqrt(2pi)*64
  const float inv_norm = 1.0f / (2.50662827463100050242f * 64.0f);
  float data = data_sum[i] * inv_norm;
  float diff = mix - data;
  float v = diff * diff;
#pragma unroll
  for (int off = 32; off > 0; off >>= 1)
    v += __shfl_xor(v, off);
  __shared__ float wsum[4];
  if ((t & 63) == 0) wsum[t >> 6] = v;
  __syncthreads();
  if (t == 0) atomicAdd(out, (wsum[0] + wsum[1]) + (wsum[2] + wsum[3]));
}

extern "C" void kernel_launch(void* const* d_in, const int* in_sizes, int n_in,
                              void* d_out, int out_size, void* d_ws, size_t ws_size,
                              hipStream_t stream) {
  const float* x     = (const float*)d_in[0];
  const float* wl    = (const float*)d_in[1];
  const float* means = (const float*)d_in[2];
  const float* lv    = (const float*)d_in[3];
  float* out = (float*)d_out;

  float* amp      = (float*)d_ws;
  float* q        = amp + KCOMP;
  float* data_sum = q + KCOMP;

  // ws/out are poisoned 0xAA before every timed launch — zero what we accumulate into.
  hipMemsetAsync(d_ws, 0, (2 * KCOMP + NPTS) * sizeof(float), stream);
  hipMemsetAsync(d_out, 0, sizeof(float), stream);

  prep_kernel<<<1, 64, 0, stream>>>(wl, lv, amp, q);
  kde_kernel<<<dim3(NPTS / IBLK, NPTS / JT), IBLK, 0, stream>>>(x, data_sum);
  final_kernel<<<NPTS / 256, 256, 0, stream>>>(x, means, amp, q, data_sum, out);
}

// Round 2
// 71.087 us; speedup vs baseline: 1.0790x; 1.0790x over previous
//
#include <hip/hip_runtime.h>
#include <math.h>

#ifndef M_PI
#define M_PI 3.14159265358979323846
#endif

#define NPTS 8192
#define KCOMP 64
#define JT 256      // j-tile per K1 block
#define IBLK 256    // i's per K1 block (= block size)
#define NJB (NPTS / JT)   // 32 j-chunks

// Force the single-instruction hardware exp2 (v_exp_f32, ~1 ulp).
__device__ __forceinline__ float fexp2(float a) {
#if __has_builtin(__builtin_amdgcn_exp2f)
  return __builtin_amdgcn_exp2f(a);
#else
  float r;
  asm("v_exp_f32 %0, %1" : "=v"(r) : "v"(a));
  return r;
#endif
}

// workspace layout (floats): part[jb*NPTS + i], jb in [0,32) -> 1 MB

// --- K1: pairwise KDE partial sums (67.1M hardware exp2) -------------------
// block(ib, jb): 256 threads, each thread one i, loops the 256-j LDS tile.
// Atomic-free: partial for (i, jb) stored at part[jb*NPTS + i].
// Also zeroes out[0] (K2's atomic target) — stream order makes this safe.
__global__ __launch_bounds__(IBLK) void kde_kernel(
    const float* __restrict__ x,
    float* __restrict__ part,
    float* __restrict__ out) {
  __shared__ alignas(16) float xs[JT];
  // kern = exp(-0.5 d^2 / bw^2) = 2^(-(s*d)^2), s = sqrt(8192 * log2(e))
  const float s = sqrtf(8192.0f * 1.44269504088896340736f);
  const int t  = threadIdx.x;
  const int ib = blockIdx.x;
  const int jb = blockIdx.y;
  const int i  = ib * IBLK + t;
  xs[t] = x[jb * JT + t] * s;     // pre-scaled j-tile
  float u = x[i] * s;             // pre-scaled own point
  if ((ib | jb | t) == 0) out[0] = 0.0f;
  __syncthreads();

  float acc0 = 0.f, acc1 = 0.f, acc2 = 0.f, acc3 = 0.f;
  const float4* xs4 = reinterpret_cast<const float4*>(xs);
#pragma unroll 4
  for (int jj = 0; jj < JT / 4; ++jj) {
    float4 v = xs4[jj];           // ds_read_b128, same-address broadcast
    float d0 = u - v.x;
    float d1 = u - v.y;
    float d2 = u - v.z;
    float d3 = u - v.w;
    acc0 += fexp2(-(d0 * d0));    // v_sub + v_mul(neg) + v_exp + v_add
    acc1 += fexp2(-(d1 * d1));
    acc2 += fexp2(-(d2 * d2));
    acc3 += fexp2(-(d3 * d3));
  }
  part[jb * NPTS + i] = (acc0 + acc1) + (acc2 + acc3);
}

// --- K2: fold partials + softmax + mixture pdf + MSE reduction -------------
__global__ __launch_bounds__(256) void final_kernel(
    const float* __restrict__ x,
    const float* __restrict__ logits,
    const float* __restrict__ means,
    const float* __restrict__ log_vars,
    const float* __restrict__ part,
    float* __restrict__ out) {
  __shared__ float sm[KCOMP], sa[KCOMP], sq[KCOMP];
  const int t = threadIdx.x;
  if (t < KCOMP) {                // exactly wave 0: softmax over K=64 via shfl
    float l = logits[t];
    float m = l;
#pragma unroll
    for (int off = 32; off > 0; off >>= 1)
      m = fmaxf(m, __shfl_xor(m, off));
    float e = expf(l - m);
    float ssum = e;
#pragma unroll
    for (int off = 32; off > 0; off >>= 1)
      ssum += __shfl_xor(ssum, off);
    float w = e / ssum;
    float var = expf(log_vars[t]);
    sm[t] = means[t];
    sa[t] = w * rsqrtf(2.0f * (float)M_PI * var);   // amplitude
    sq[t] = 0.72134752044448170368f / var;          // 0.5*log2(e)/var
  }
  __syncthreads();

  const int i = blockIdx.x * 256 + t;
  // fold the 32 j-chunk partials (coalesced: stride NPTS rows)
  float ds = 0.f;
#pragma unroll
  for (int jb = 0; jb < NJB; ++jb)
    ds += part[jb * NPTS + i];
  // data_pdf = ds / (sqrt(2*pi)*bw*N), bw*N = 64
  const float inv_norm = 1.0f / (2.50662827463100050242f * 64.0f);
  float data = ds * inv_norm;

  const float xi = x[i];
  float mix = 0.f;
#pragma unroll 8
  for (int k = 0; k < KCOMP; ++k) {
    float d = xi - sm[k];
    mix += sa[k] * fexp2(-(sq[k] * d) * d);
  }

  float diff = mix - data;
  float v = diff * diff;
#pragma unroll
  for (int off = 32; off > 0; off >>= 1)
    v += __shfl_xor(v, off);
  __shared__ float wsum[4];
  if ((t & 63) == 0) wsum[t >> 6] = v;
  __syncthreads();
  if (t == 0) atomicAdd(out, (wsum[0] + wsum[1]) + (wsum[2] + wsum[3]));
}

extern "C" void kernel_launch(void* const* d_in, const int* in_sizes, int n_in,
                              void* d_out, int out_size, void* d_ws, size_t ws_size,
                              hipStream_t stream) {
  const float* x     = (const float*)d_in[0];
  const float* wl    = (const float*)d_in[1];
  const float* means = (const float*)d_in[2];
  const float* lv    = (const float*)d_in[3];
  float* out  = (float*)d_out;
  float* part = (float*)d_ws;   // 32 * 8192 floats = 1 MB, fully overwritten by K1

  kde_kernel<<<dim3(NPTS / IBLK, NJB), IBLK, 0, stream>>>(x, part, out);
  final_kernel<<<NPTS / 256, 256, 0, stream>>>(x, wl, means, lv, part, out);
}